// Round 16
// baseline (3471.733 us; speedup 1.0000x reference)
//
#include <hip/hip_runtime.h>
#include <hip/hip_fp16.h>
#include <cstddef>
#include <cstdint>

#define H100  100
#define G4    400
#define BATCH 16
#define TTOT  4096
#define NIN   40
#define TAU   128   // timesteps per xg block (W staging amortized 8x vs 16)

__device__ __forceinline__ float fast_rcp(float x) { return __builtin_amdgcn_rcpf(x); }

__device__ __forceinline__ float gate_act(float z, bool is_g) {
    float m = is_g ? -2.0f : -1.0f;
    float e = __expf(m * z);
    float r = fast_rcp(1.0f + e);
    return is_g ? (2.0f * r - 1.0f) : r;
}
__device__ __forceinline__ float tanh_fast(float x) {
    float e = __expf(-2.0f * x);
    float r = fast_rcp(1.0f + e);
    return 2.0f * r - 1.0f;
}

// ---------------------------------------------------------------------------
// Kernel 1: xg[b][t][g] = sum_i x[b][t][i]*W_ih[g][i] + b_ih[g] + b_hh[g]
// Output in f16 (halves write + lstm-read traffic; |xg|<~2, rel err 5e-4 --
// same order as the f16 weight rounding already accepted).
// TAU=128 timesteps/block: the 64KB W_ih LDS stage is amortized 8x vs R13.
// ---------------------------------------------------------------------------
__global__ __launch_bounds__(256) void xg_kernel(
    const float* __restrict__ x, const float* __restrict__ W_ih,
    const float* __restrict__ b_ih, const float* __restrict__ b_hh,
    __half* __restrict__ xg, int t0, int steps, int chunkT)
{
    __shared__ float W_lds[NIN * G4];     // transposed [i][g], 64 KB
    __shared__ float x_lds[TAU * NIN];    // 20.5 KB
    __shared__ float bias_lds[G4];

    int tid = threadIdx.x;
    int blocks_per_b = (steps + TAU - 1) / TAU;
    int b   = blockIdx.x / blocks_per_b;
    int tt  = blockIdx.x % blocks_per_b;
    int lt0 = tt * TAU;
    int ntau = min(TAU, steps - lt0);

    for (int p = tid; p < NIN * G4; p += 256) {
        int g = p / NIN, i = p % NIN;
        W_lds[i * G4 + g] = W_ih[p];
    }
    for (int p = tid; p < G4; p += 256) bias_lds[p] = b_ih[p] + b_hh[p];
    const float* xsrc = x + ((size_t)b * TTOT + (size_t)(t0 + lt0)) * NIN;
    for (int p = tid; p < ntau * NIN; p += 256) x_lds[p] = xsrc[p];
    __syncthreads();

    int ntask = ntau * G4;
    for (int p = tid; p < ntask; p += 256) {
        int tau = p / G4, g = p % G4;
        float acc = bias_lds[g];
        #pragma unroll
        for (int i = 0; i < NIN; i++)
            acc = fmaf(x_lds[tau * NIN + i], W_lds[i * G4 + g], acc);
        xg[((size_t)b * chunkT + (size_t)(lt0 + tau)) * G4 + g] = __float2half(acc);
    }
}

// ---------------------------------------------------------------------------
// Kernel 2: LSTM scan. R13 structure VERBATIM (best measured: 2548 us,
// reverting R15's pk_fma regression): 16 blocks, 256 threads (4 waves,
// 1/SIMD via waves_per_eu(1,1)). Thread x owns rows x and x+256 as PACKED
// f16 pairs (v_dot2_f32_f16, f32 accum; VGPR_Count 132, register-resident).
// Raw lgkmcnt(0)+s_barrier (no vmcnt drain). Only change: xg read as f16.
//
// Floor analysis (R8..R15): per step ~380cy per-SIMD issue (~190 instr x
// 2cy) + ~370cy unhideable serial chain (barrier, ds_read 120cy, update,
// pack, readlane) at ~1.2GHz low-occupancy DVFS clock = 622ns/step.
// Alternatives all analyzed >= equal: MFMA one-block (dot wins, epilogue
// concentrates 16x -> net zero), single-wave (313 weight VGPR/lane
// infeasible), channel-owner (2x dot issue for one LDS read saved).
// ---------------------------------------------------------------------------
using h2_t = decltype(__builtin_amdgcn_cvt_pkrtz(0.0f, 0.0f));

__device__ __forceinline__ int h2i(h2_t v) { int r; __builtin_memcpy(&r, &v, 4); return r; }
__device__ __forceinline__ h2_t i2h(int v) { h2_t r; __builtin_memcpy(&r, &v, 4); return r; }

#if __has_builtin(__builtin_amdgcn_fdot2)
__device__ __forceinline__ float fdot2(h2_t a, h2_t b, float c) {
    return __builtin_amdgcn_fdot2(a, b, c, false);
}
#else
__device__ __forceinline__ float fdot2(h2_t a, h2_t b, float c) {
    float d;
    asm("v_dot2_f32_f16 %0, %1, %2, %3" : "=v"(d) : "v"(a), "v"(b), "v"(c));
    return d;
}
#endif

#define PIN1(a) asm volatile("" : "+v"(a))

__global__ __launch_bounds__(256)
__attribute__((amdgpu_waves_per_eu(1, 1)))
void lstm_kernel(
    const __half* __restrict__ xg, const float* __restrict__ W_hh,
    float* __restrict__ hc, int t0, int steps, int chunkT)
{
    __shared__ float a_lds[2][G4];

    const int x = threadIdx.x;
    const int b = blockIdx.x;
    const int l = x & 63;
    const bool hasB = (x < G4 - 256);          // x < 144: second row valid
    const int  rA = x;
    const int  rB = hasB ? (x + 256) : 0;      // clamp for safe addressing

    const float2* wra2 = (const float2*)(W_hh + (size_t)rA * H100);
    const float2* wrb2 = (const float2*)(W_hh + (size_t)rB * H100);
#define LDW(q) \
    int wa##q = h2i(__builtin_amdgcn_cvt_pkrtz(wra2[q].x, wra2[q].y)); \
    int wb##q = h2i(__builtin_amdgcn_cvt_pkrtz(wrb2[q].x, wrb2[q].y)); \
    PIN1(wa##q); PIN1(wb##q);
    LDW(0)  LDW(1)  LDW(2)  LDW(3)  LDW(4)  LDW(5)  LDW(6)  LDW(7)
    LDW(8)  LDW(9)  LDW(10) LDW(11) LDW(12) LDW(13) LDW(14) LDW(15)
    LDW(16) LDW(17) LDW(18) LDW(19) LDW(20) LDW(21) LDW(22) LDW(23)
    LDW(24) LDW(25) LDW(26) LDW(27) LDW(28) LDW(29) LDW(30) LDW(31)
    LDW(32) LDW(33) LDW(34) LDW(35) LDW(36) LDW(37) LDW(38) LDW(39)
    LDW(40) LDW(41) LDW(42) LDW(43) LDW(44) LDW(45) LDW(46) LDW(47)
    LDW(48) LDW(49)
#undef LDW

    float* hch = hc;                        // h state [16][100]
    float* hcc = hc + BATCH * H100;         // c state [16][100]

    // replicated fp32 state: lane l (<50) owns channels 2l, 2l+1
    float h0 = 0.f, h1 = 0.f, c0 = 0.f, c1 = 0.f;
    int hpi = 0;                            // packed half2 of (h0,h1)
    if (l < 50) {
        if (t0 != 0) {
            float2 hv = ((const float2*)(hch + b * H100))[l];
            float2 cv = ((const float2*)(hcc + b * H100))[l];
            h0 = hv.x; h1 = hv.y; c0 = cv.x; c1 = cv.y;
        }
        hpi = h2i(__builtin_amdgcn_cvt_pkrtz(h0, h1));
    }

    const __half* xgb = xg + (size_t)b * chunkT * G4;
    float xcA = __half2float(xgb[rA]);
    float xcB = hasB ? __half2float(xgb[rB]) : 0.0f;

    const bool is_gA = (x >= 200) && (x < 300);
    const bool is_gB = (x < 44);               // row x+256 in [200,300)

#define RLH2(src, idx) i2h(__builtin_amdgcn_readlane((src), (idx)))
#define DOTQ(q, aA, aB) { const h2_t u = RLH2(hpi, q); \
    aA = fdot2(i2h(wa##q), u, aA); \
    aB = fdot2(i2h(wb##q), u, aB); }

    #pragma unroll 1
    for (int t = 0; t < steps; t++) {
        // prefetch next step's xg; stays in flight across the raw barrier
        float nxA = 0.f, nxB = 0.f;
        if (t + 1 < steps) {
            const __half* p = xgb + (size_t)(t + 1) * G4;
            nxA = __half2float(p[rA]);
            nxB = __half2float(p[rB]);
        }

        float aA0 = 0, aA1 = 0, aB0 = 0, aB1 = 0;
        DOTQ(0,  aA0, aB0) DOTQ(1,  aA1, aB1) DOTQ(2,  aA0, aB0) DOTQ(3,  aA1, aB1)
        DOTQ(4,  aA0, aB0) DOTQ(5,  aA1, aB1) DOTQ(6,  aA0, aB0) DOTQ(7,  aA1, aB1)
        DOTQ(8,  aA0, aB0) DOTQ(9,  aA1, aB1) DOTQ(10, aA0, aB0) DOTQ(11, aA1, aB1)
        DOTQ(12, aA0, aB0) DOTQ(13, aA1, aB1) DOTQ(14, aA0, aB0) DOTQ(15, aA1, aB1)
        DOTQ(16, aA0, aB0) DOTQ(17, aA1, aB1) DOTQ(18, aA0, aB0) DOTQ(19, aA1, aB1)
        DOTQ(20, aA0, aB0) DOTQ(21, aA1, aB1) DOTQ(22, aA0, aB0) DOTQ(23, aA1, aB1)
        DOTQ(24, aA0, aB0) DOTQ(25, aA1, aB1) DOTQ(26, aA0, aB0) DOTQ(27, aA1, aB1)
        DOTQ(28, aA0, aB0) DOTQ(29, aA1, aB1) DOTQ(30, aA0, aB0) DOTQ(31, aA1, aB1)
        DOTQ(32, aA0, aB0) DOTQ(33, aA1, aB1) DOTQ(34, aA0, aB0) DOTQ(35, aA1, aB1)
        DOTQ(36, aA0, aB0) DOTQ(37, aA1, aB1) DOTQ(38, aA0, aB0) DOTQ(39, aA1, aB1)
        DOTQ(40, aA0, aB0) DOTQ(41, aA1, aB1) DOTQ(42, aA0, aB0) DOTQ(43, aA1, aB1)
        DOTQ(44, aA0, aB0) DOTQ(45, aA1, aB1) DOTQ(46, aA0, aB0) DOTQ(47, aA1, aB1)
        DOTQ(48, aA0, aB0) DOTQ(49, aA1, aB1)

        float zA = xcA + (aA0 + aA1);
        float zB = xcB + (aB0 + aB1);

        const int par = t & 1;
        a_lds[par][rA] = gate_act(zA, is_gA);
        if (hasB) a_lds[par][x + 256] = gate_act(zB, is_gB);
        // Producer-side visibility only: drain LDS counter, raw barrier.
        asm volatile("s_waitcnt lgkmcnt(0)" ::: "memory");
        __builtin_amdgcn_s_barrier();

        // every wave redundantly updates the full c/h state in fp32 registers
        if (l < 50) {
            const float* ab = a_lds[par];
            float2 gi = ((const float2*)(ab))[l];
            float2 gf = ((const float2*)(ab + 100))[l];
            float2 gg = ((const float2*)(ab + 200))[l];
            float2 go = ((const float2*)(ab + 300))[l];
            c0 = fmaf(gf.x, c0, gi.x * gg.x);
            c1 = fmaf(gf.y, c1, gi.y * gg.y);
            h0 = go.x * tanh_fast(c0);
            h1 = go.y * tanh_fast(c1);
            hpi = h2i(__builtin_amdgcn_cvt_pkrtz(h0, h1));
        }
        xcA = nxA; xcB = nxB;
    }

    if (x < 64 && l < 50) {             // wave 0 writes the carried state
        ((float2*)(hch + b * H100))[l] = make_float2(h0, h1);
        ((float2*)(hcc + b * H100))[l] = make_float2(c0, c1);
    }
#undef DOTQ
#undef RLH2
}

// ---------------------------------------------------------------------------
// Kernel 3: head. y1 = h @ W1^T + b1; BatchNorm (training mode, biased var,
// batch of 16); out = y1n @ W2^T + b2. One block.
// ---------------------------------------------------------------------------
__global__ __launch_bounds__(256) void head_kernel(
    const float* __restrict__ hc, const float* __restrict__ W1,
    const float* __restrict__ b1, const float* __restrict__ gamma,
    const float* __restrict__ beta, const float* __restrict__ W2,
    const float* __restrict__ b2, float* __restrict__ out)
{
    __shared__ float h_s[BATCH * H100];
    __shared__ float W1_s[H100 * 101];     // padded rows: conflict-free
    __shared__ float y1_s[BATCH * H100];
    __shared__ float W2_s[40 * 101];
    __shared__ float scale_s[H100], shift_s[H100];

    int tid = threadIdx.x;
    for (int p = tid; p < BATCH * H100; p += 256) h_s[p] = hc[p];
    for (int p = tid; p < H100 * H100; p += 256)
        W1_s[(p / H100) * 101 + p % H100] = W1[p];
    for (int p = tid; p < 40 * H100; p += 256)
        W2_s[(p / H100) * 101 + p % H100] = W2[p];
    __syncthreads();

    for (int p = tid; p < BATCH * H100; p += 256) {
        int b = p / H100, j = p % H100;
        float acc = b1[j];
        for (int k = 0; k < H100; k++)
            acc = fmaf(h_s[b * H100 + k], W1_s[j * 101 + k], acc);
        y1_s[b * H100 + j] = acc;
    }
    __syncthreads();

    if (tid < H100) {
        float mu = 0.0f;
        for (int b = 0; b < BATCH; b++) mu += y1_s[b * H100 + tid];
        mu *= (1.0f / BATCH);
        float var = 0.0f;
        for (int b = 0; b < BATCH; b++) {
            float d = y1_s[b * H100 + tid] - mu;
            var = fmaf(d, d, var);
        }
        var *= (1.0f / BATCH);
        float sc = gamma[tid] * rsqrtf(var + 1e-5f);
        scale_s[tid] = sc;
        shift_s[tid] = beta[tid] - mu * sc;
    }
    __syncthreads();

    for (int p = tid; p < BATCH * 40; p += 256) {
        int b = p / 40, o = p % 40;
        float acc = b2[o];
        for (int k = 0; k < H100; k++)
            acc = fmaf(fmaf(y1_s[b * H100 + k], scale_s[k], shift_s[k]),
                       W2_s[o * 101 + k], acc);
        out[p] = acc;
    }
}

// ---------------------------------------------------------------------------
extern "C" void kernel_launch(void* const* d_in, const int* in_sizes, int n_in,
                              void* d_out, int out_size, void* d_ws, size_t ws_size,
                              hipStream_t stream)
{
    const float* x     = (const float*)d_in[0];
    const float* W_ih  = (const float*)d_in[1];
    const float* W_hh  = (const float*)d_in[2];
    const float* b_ih  = (const float*)d_in[3];
    const float* b_hh  = (const float*)d_in[4];
    const float* W1    = (const float*)d_in[5];
    const float* b1    = (const float*)d_in[6];
    const float* gamma = (const float*)d_in[7];
    const float* beta  = (const float*)d_in[8];
    const float* W2    = (const float*)d_in[9];
    const float* b2    = (const float*)d_in[10];
    float* out = (float*)d_out;

    // ws layout: [0,16384) h/c state, [16384, ...) xg ring buffer (f16)
    float*  hc = (float*)d_ws;
    __half* xg = (__half*)((char*)d_ws + 16384);
    size_t avail    = ws_size > 16384 ? ws_size - 16384 : 0;
    size_t per_step = (size_t)BATCH * G4 * sizeof(__half);  // 12800 B
    size_t ct       = (avail / per_step) & ~(size_t)(TAU - 1);
    int chunkT = ct > TTOT ? TTOT : (int)ct;
    if (chunkT < TAU) chunkT = TAU;   // minimal ring

    for (int t0 = 0; t0 < TTOT; t0 += chunkT) {
        int steps = (TTOT - t0 < chunkT) ? (TTOT - t0) : chunkT;
        int bpb = (steps + TAU - 1) / TAU;
        xg_kernel<<<dim3(BATCH * bpb), 256, 0, stream>>>(
            x, W_ih, b_ih, b_hh, xg, t0, steps, chunkT);
        lstm_kernel<<<dim3(BATCH), 256, 0, stream>>>(
            xg, W_hh, hc, t0, steps, chunkT);
    }
    head_kernel<<<1, 256, 0, stream>>>(hc, W1, b1, gamma, beta, W2, b2, out);
}

// Round 18
// 2718.146 us; speedup vs baseline: 1.2772x; 1.2772x over previous
//
#include <hip/hip_runtime.h>
#include <cstddef>
#include <cstdint>

#define H100  100
#define G4    400
#define BATCH 16
#define TTOT  4096
#define NIN   40
#define TAU   128   // timesteps per xg block (W staging amortized 8x vs 16)

__device__ __forceinline__ float fast_rcp(float x) { return __builtin_amdgcn_rcpf(x); }

__device__ __forceinline__ float gate_act(float z, bool is_g) {
    float m = is_g ? -2.0f : -1.0f;
    float e = __expf(m * z);
    float r = fast_rcp(1.0f + e);
    return is_g ? (2.0f * r - 1.0f) : r;
}
__device__ __forceinline__ float tanh_fast(float x) {
    float e = __expf(-2.0f * x);
    float r = fast_rcp(1.0f + e);
    return 2.0f * r - 1.0f;
}

// ---------------------------------------------------------------------------
// Kernel 1: xg[b][t][g] = sum_i x[b][t][i]*W_ih[g][i] + b_ih[g] + b_hh[g]
// f32 output (R16 f16 experiment: halved FETCH but dragged the lstm's vmcnt
// wait mid-step via the load-site cvt -> +750us. FETCH was never the
// bottleneck at 0.26% of peak; latency placement is.)
// TAU=128 timesteps/block: 64KB W_ih LDS stage amortized 8x vs R13.
// ---------------------------------------------------------------------------
__global__ __launch_bounds__(256) void xg_kernel(
    const float* __restrict__ x, const float* __restrict__ W_ih,
    const float* __restrict__ b_ih, const float* __restrict__ b_hh,
    float* __restrict__ xg, int t0, int steps, int chunkT)
{
    __shared__ float W_lds[NIN * G4];     // transposed [i][g], 64 KB
    __shared__ float x_lds[TAU * NIN];    // 20.5 KB
    __shared__ float bias_lds[G4];

    int tid = threadIdx.x;
    int blocks_per_b = (steps + TAU - 1) / TAU;
    int b   = blockIdx.x / blocks_per_b;
    int tt  = blockIdx.x % blocks_per_b;
    int lt0 = tt * TAU;
    int ntau = min(TAU, steps - lt0);

    for (int p = tid; p < NIN * G4; p += 256) {
        int g = p / NIN, i = p % NIN;
        W_lds[i * G4 + g] = W_ih[p];
    }
    for (int p = tid; p < G4; p += 256) bias_lds[p] = b_ih[p] + b_hh[p];
    const float* xsrc = x + ((size_t)b * TTOT + (size_t)(t0 + lt0)) * NIN;
    for (int p = tid; p < ntau * NIN; p += 256) x_lds[p] = xsrc[p];
    __syncthreads();

    int ntask = ntau * G4;
    for (int p = tid; p < ntask; p += 256) {
        int tau = p / G4, g = p % G4;
        float acc = bias_lds[g];
        #pragma unroll
        for (int i = 0; i < NIN; i++)
            acc = fmaf(x_lds[tau * NIN + i], W_lds[i * G4 + g], acc);
        xg[((size_t)b * chunkT + (size_t)(lt0 + tau)) * G4 + g] = acc;
    }
}

// ---------------------------------------------------------------------------
// Kernel 2: LSTM scan. R13 VERBATIM (best measured: 2548 us): 16 blocks,
// 256 threads (4 waves, 1/SIMD via waves_per_eu(1,1)). Thread x owns rows
// x and x+256 as PACKED f16 pairs (v_dot2_f32_f16, f32 accum; VGPR 132,
// register-resident). Raw lgkmcnt(0)+s_barrier (no vmcnt drain). f32 xg
// prefetch whose only consumer is next step's add -> vmcnt wait parks a
// full step after issue (R16 lesson: f16+cvt pulls it mid-step, +30%).
//
// Floor analysis (R8..R16): per step ~380cy per-SIMD issue (~190 instr x
// 2cy) + ~370cy unhideable serial chain (barrier, ds_read ~120cy, update,
// pack, readlane) at low-occupancy DVFS clock ~1.2GHz = 622ns/step.
// Alternatives analyzed >= equal: MFMA one-block (dot wins, epilogue
// concentrates 16x -> net zero), single-wave (313 weight VGPR/lane
// infeasible), channel-owner (2x dot issue for one LDS read saved),
// pk_fma (R15: +flush instrs = +5%), RL-pipelining (R14: null, compiler
// already schedules it), raw-barrier (R13: null, vmcnt never the stall).
// ---------------------------------------------------------------------------
using h2_t = decltype(__builtin_amdgcn_cvt_pkrtz(0.0f, 0.0f));

__device__ __forceinline__ int h2i(h2_t v) { int r; __builtin_memcpy(&r, &v, 4); return r; }
__device__ __forceinline__ h2_t i2h(int v) { h2_t r; __builtin_memcpy(&r, &v, 4); return r; }

#if __has_builtin(__builtin_amdgcn_fdot2)
__device__ __forceinline__ float fdot2(h2_t a, h2_t b, float c) {
    return __builtin_amdgcn_fdot2(a, b, c, false);
}
#else
__device__ __forceinline__ float fdot2(h2_t a, h2_t b, float c) {
    float d;
    asm("v_dot2_f32_f16 %0, %1, %2, %3" : "=v"(d) : "v"(a), "v"(b), "v"(c));
    return d;
}
#endif

#define PIN1(a) asm volatile("" : "+v"(a))

__global__ __launch_bounds__(256)
__attribute__((amdgpu_waves_per_eu(1, 1)))
void lstm_kernel(
    const float* __restrict__ xg, const float* __restrict__ W_hh,
    float* __restrict__ hc, int t0, int steps, int chunkT)
{
    __shared__ float a_lds[2][G4];

    const int x = threadIdx.x;
    const int b = blockIdx.x;
    const int l = x & 63;
    const bool hasB = (x < G4 - 256);          // x < 144: second row valid
    const int  rA = x;
    const int  rB = hasB ? (x + 256) : 0;      // clamp for safe addressing

    const float2* wra2 = (const float2*)(W_hh + (size_t)rA * H100);
    const float2* wrb2 = (const float2*)(W_hh + (size_t)rB * H100);
#define LDW(q) \
    int wa##q = h2i(__builtin_amdgcn_cvt_pkrtz(wra2[q].x, wra2[q].y)); \
    int wb##q = h2i(__builtin_amdgcn_cvt_pkrtz(wrb2[q].x, wrb2[q].y)); \
    PIN1(wa##q); PIN1(wb##q);
    LDW(0)  LDW(1)  LDW(2)  LDW(3)  LDW(4)  LDW(5)  LDW(6)  LDW(7)
    LDW(8)  LDW(9)  LDW(10) LDW(11) LDW(12) LDW(13) LDW(14) LDW(15)
    LDW(16) LDW(17) LDW(18) LDW(19) LDW(20) LDW(21) LDW(22) LDW(23)
    LDW(24) LDW(25) LDW(26) LDW(27) LDW(28) LDW(29) LDW(30) LDW(31)
    LDW(32) LDW(33) LDW(34) LDW(35) LDW(36) LDW(37) LDW(38) LDW(39)
    LDW(40) LDW(41) LDW(42) LDW(43) LDW(44) LDW(45) LDW(46) LDW(47)
    LDW(48) LDW(49)
#undef LDW

    float* hch = hc;                        // h state [16][100]
    float* hcc = hc + BATCH * H100;         // c state [16][100]

    // replicated fp32 state: lane l (<50) owns channels 2l, 2l+1
    float h0 = 0.f, h1 = 0.f, c0 = 0.f, c1 = 0.f;
    int hpi = 0;                            // packed half2 of (h0,h1)
    if (l < 50) {
        if (t0 != 0) {
            float2 hv = ((const float2*)(hch + b * H100))[l];
            float2 cv = ((const float2*)(hcc + b * H100))[l];
            h0 = hv.x; h1 = hv.y; c0 = cv.x; c1 = cv.y;
        }
        hpi = h2i(__builtin_amdgcn_cvt_pkrtz(h0, h1));
    }

    const float* xgb = xg + (size_t)b * chunkT * G4;
    float xcA = xgb[rA];
    float xcB = hasB ? xgb[rB] : 0.0f;

    const bool is_gA = (x >= 200) && (x < 300);
    const bool is_gB = (x < 44);               // row x+256 in [200,300)

#define RLH2(src, idx) i2h(__builtin_amdgcn_readlane((src), (idx)))
#define DOTQ(q, aA, aB) { const h2_t u = RLH2(hpi, q); \
    aA = fdot2(i2h(wa##q), u, aA); \
    aB = fdot2(i2h(wb##q), u, aB); }

    #pragma unroll 1
    for (int t = 0; t < steps; t++) {
        // prefetch next step's xg; stays in flight across the raw barrier
        float nxA = 0.f, nxB = 0.f;
        if (t + 1 < steps) {
            const float* p = xgb + (size_t)(t + 1) * G4;
            nxA = p[rA];
            nxB = p[rB];
        }

        float aA0 = 0, aA1 = 0, aB0 = 0, aB1 = 0;
        DOTQ(0,  aA0, aB0) DOTQ(1,  aA1, aB1) DOTQ(2,  aA0, aB0) DOTQ(3,  aA1, aB1)
        DOTQ(4,  aA0, aB0) DOTQ(5,  aA1, aB1) DOTQ(6,  aA0, aB0) DOTQ(7,  aA1, aB1)
        DOTQ(8,  aA0, aB0) DOTQ(9,  aA1, aB1) DOTQ(10, aA0, aB0) DOTQ(11, aA1, aB1)
        DOTQ(12, aA0, aB0) DOTQ(13, aA1, aB1) DOTQ(14, aA0, aB0) DOTQ(15, aA1, aB1)
        DOTQ(16, aA0, aB0) DOTQ(17, aA1, aB1) DOTQ(18, aA0, aB0) DOTQ(19, aA1, aB1)
        DOTQ(20, aA0, aB0) DOTQ(21, aA1, aB1) DOTQ(22, aA0, aB0) DOTQ(23, aA1, aB1)
        DOTQ(24, aA0, aB0) DOTQ(25, aA1, aB1) DOTQ(26, aA0, aB0) DOTQ(27, aA1, aB1)
        DOTQ(28, aA0, aB0) DOTQ(29, aA1, aB1) DOTQ(30, aA0, aB0) DOTQ(31, aA1, aB1)
        DOTQ(32, aA0, aB0) DOTQ(33, aA1, aB1) DOTQ(34, aA0, aB0) DOTQ(35, aA1, aB1)
        DOTQ(36, aA0, aB0) DOTQ(37, aA1, aB1) DOTQ(38, aA0, aB0) DOTQ(39, aA1, aB1)
        DOTQ(40, aA0, aB0) DOTQ(41, aA1, aB1) DOTQ(42, aA0, aB0) DOTQ(43, aA1, aB1)
        DOTQ(44, aA0, aB0) DOTQ(45, aA1, aB1) DOTQ(46, aA0, aB0) DOTQ(47, aA1, aB1)
        DOTQ(48, aA0, aB0) DOTQ(49, aA1, aB1)

        float zA = xcA + (aA0 + aA1);
        float zB = xcB + (aB0 + aB1);

        const int par = t & 1;
        a_lds[par][rA] = gate_act(zA, is_gA);
        if (hasB) a_lds[par][x + 256] = gate_act(zB, is_gB);
        // Producer-side visibility only: drain LDS counter, raw barrier.
        asm volatile("s_waitcnt lgkmcnt(0)" ::: "memory");
        __builtin_amdgcn_s_barrier();

        // every wave redundantly updates the full c/h state in fp32 registers
        if (l < 50) {
            const float* ab = a_lds[par];
            float2 gi = ((const float2*)(ab))[l];
            float2 gf = ((const float2*)(ab + 100))[l];
            float2 gg = ((const float2*)(ab + 200))[l];
            float2 go = ((const float2*)(ab + 300))[l];
            c0 = fmaf(gf.x, c0, gi.x * gg.x);
            c1 = fmaf(gf.y, c1, gi.y * gg.y);
            h0 = go.x * tanh_fast(c0);
            h1 = go.y * tanh_fast(c1);
            hpi = h2i(__builtin_amdgcn_cvt_pkrtz(h0, h1));
        }
        xcA = nxA; xcB = nxB;
    }

    if (x < 64 && l < 50) {             // wave 0 writes the carried state
        ((float2*)(hch + b * H100))[l] = make_float2(h0, h1);
        ((float2*)(hcc + b * H100))[l] = make_float2(c0, c1);
    }
#undef DOTQ
#undef RLH2
}

// ---------------------------------------------------------------------------
// Kernel 3: head. y1 = h @ W1^T + b1; BatchNorm (training mode, biased var,
// batch of 16); out = y1n @ W2^T + b2. One block.
// ---------------------------------------------------------------------------
__global__ __launch_bounds__(256) void head_kernel(
    const float* __restrict__ hc, const float* __restrict__ W1,
    const float* __restrict__ b1, const float* __restrict__ gamma,
    const float* __restrict__ beta, const float* __restrict__ W2,
    const float* __restrict__ b2, float* __restrict__ out)
{
    __shared__ float h_s[BATCH * H100];
    __shared__ float W1_s[H100 * 101];     // padded rows: conflict-free
    __shared__ float y1_s[BATCH * H100];
    __shared__ float W2_s[40 * 101];
    __shared__ float scale_s[H100], shift_s[H100];

    int tid = threadIdx.x;
    for (int p = tid; p < BATCH * H100; p += 256) h_s[p] = hc[p];
    for (int p = tid; p < H100 * H100; p += 256)
        W1_s[(p / H100) * 101 + p % H100] = W1[p];
    for (int p = tid; p < 40 * H100; p += 256)
        W2_s[(p / H100) * 101 + p % H100] = W2[p];
    __syncthreads();

    for (int p = tid; p < BATCH * H100; p += 256) {
        int b = p / H100, j = p % H100;
        float acc = b1[j];
        for (int k = 0; k < H100; k++)
            acc = fmaf(h_s[b * H100 + k], W1_s[j * 101 + k], acc);
        y1_s[b * H100 + j] = acc;
    }
    __syncthreads();

    if (tid < H100) {
        float mu = 0.0f;
        for (int b = 0; b < BATCH; b++) mu += y1_s[b * H100 + tid];
        mu *= (1.0f / BATCH);
        float var = 0.0f;
        for (int b = 0; b < BATCH; b++) {
            float d = y1_s[b * H100 + tid] - mu;
            var = fmaf(d, d, var);
        }
        var *= (1.0f / BATCH);
        float sc = gamma[tid] * rsqrtf(var + 1e-5f);
        scale_s[tid] = sc;
        shift_s[tid] = beta[tid] - mu * sc;
    }
    __syncthreads();

    for (int p = tid; p < BATCH * 40; p += 256) {
        int b = p / 40, o = p % 40;
        float acc = b2[o];
        for (int k = 0; k < H100; k++)
            acc = fmaf(fmaf(y1_s[b * H100 + k], scale_s[k], shift_s[k]),
                       W2_s[o * 101 + k], acc);
        out[p] = acc;
    }
}

// ---------------------------------------------------------------------------
extern "C" void kernel_launch(void* const* d_in, const int* in_sizes, int n_in,
                              void* d_out, int out_size, void* d_ws, size_t ws_size,
                              hipStream_t stream)
{
    const float* x     = (const float*)d_in[0];
    const float* W_ih  = (const float*)d_in[1];
    const float* W_hh  = (const float*)d_in[2];
    const float* b_ih  = (const float*)d_in[3];
    const float* b_hh  = (const float*)d_in[4];
    const float* W1    = (const float*)d_in[5];
    const float* b1    = (const float*)d_in[6];
    const float* gamma = (const float*)d_in[7];
    const float* beta  = (const float*)d_in[8];
    const float* W2    = (const float*)d_in[9];
    const float* b2    = (const float*)d_in[10];
    float* out = (float*)d_out;

    // ws layout: [0,16384) h/c state, [16384, ...) xg ring buffer (f32)
    float* hc = (float*)d_ws;
    float* xg = (float*)((char*)d_ws + 16384);
    size_t avail    = ws_size > 16384 ? ws_size - 16384 : 0;
    size_t per_step = (size_t)BATCH * G4 * sizeof(float);  // 25600 B
    size_t ct       = (avail / per_step) & ~(size_t)(TAU - 1);
    int chunkT = ct > TTOT ? TTOT : (int)ct;
    if (chunkT < TAU) chunkT = TAU;   // minimal ring

    for (int t0 = 0; t0 < TTOT; t0 += chunkT) {
        int steps = (TTOT - t0 < chunkT) ? (TTOT - t0) : chunkT;
        int bpb = (steps + TAU - 1) / TAU;
        xg_kernel<<<dim3(BATCH * bpb), 256, 0, stream>>>(
            x, W_ih, b_ih, b_hh, xg, t0, steps, chunkT);
        lstm_kernel<<<dim3(BATCH), 256, 0, stream>>>(
            xg, W_hh, hc, t0, steps, chunkT);
    }
    head_kernel<<<1, 256, 0, stream>>>(hc, W1, b1, gamma, beta, W2, b2, out);
}